// Round 1
// baseline (381.956 us; speedup 1.0000x reference)
//
#include <hip/hip_runtime.h>
#include <hip/hip_bf16.h>
#include <stdint.h>

#define L_SEQ 2048
#define NB    4
#define NH    16
#define EH    64
#define DM    1024
#define MTOT  (NB * L_SEQ)   // 8192

typedef __attribute__((ext_vector_type(8))) short bf16x8;
typedef __attribute__((ext_vector_type(4))) float f32x4;

static __device__ __forceinline__ float bf2f(short u) {
    union { unsigned int i; float f; } c;
    c.i = ((unsigned int)(unsigned short)u) << 16;
    return c.f;
}
static __device__ __forceinline__ short f2bf(float f) {
    union { float f; unsigned int i; } c; c.f = f;
    unsigned int x = c.i;
    unsigned int r = (x + 0x7fffu + ((x >> 16) & 1u)) >> 16;
    return (short)(unsigned short)r;
}

// async global->LDS, 16B per lane; lds base must be wave-uniform (HW adds lane*16)
static __device__ __forceinline__ void gload_lds16(const void* g, void* lds) {
    __builtin_amdgcn_global_load_lds(
        (const __attribute__((address_space(1))) unsigned int*)g,
        (__attribute__((address_space(3))) unsigned int*)lds, 16, 0, 0);
}

// ---------------- elementwise fp32 -> bf16 ----------------
__global__ __launch_bounds__(256) void cvt_k(const float* __restrict__ in,
                                             short* __restrict__ out, int n4) {
    int i = blockIdx.x * 256 + threadIdx.x;
    if (i >= n4) return;
    float4 v = ((const float4*)in)[i];
    short4 o;
    o.x = f2bf(v.x); o.y = f2bf(v.y); o.z = f2bf(v.z); o.w = f2bf(v.w);
    ((short4*)out)[i] = o;
}

// ---------------- RoPE cos/sin table: [L][32] cos then [L][32] sin ----------------
__global__ __launch_bounds__(256) void rope_table_k(float* __restrict__ tab) {
    int i = blockIdx.x * 256 + threadIdx.x;   // 65536
    int l = i >> 5, d = i & 31;
    float inv = powf(10000.0f, -(float)d * (1.0f / 32.0f));
    float fr = (float)l * inv;
    tab[i]         = cosf(fr);
    tab[65536 + i] = sinf(fr);
}

// ---------------- GEMM C = A * Bt^T + bias ; A[M][K], Bt[N][K] row-major ----------------
// 128x128 tile, BK=64, 4 waves in 2x2 quadrants, mfma 16x16x32 bf16
template<int OUTBF16>
__global__ __launch_bounds__(256) void gemm_bt_k(const short* __restrict__ A,
                                                 const short* __restrict__ Bt,
                                                 const float* __restrict__ bias,
                                                 void* __restrict__ Cv,
                                                 int N, int K) {
    __shared__ short As[128 * 64];
    __shared__ short Bs[128 * 64];
    const int t = threadIdx.x;
    const int w = t >> 6, l = t & 63;
    const int wr = w >> 1, wc = w & 1;
    const int lr = l & 15, lh = l >> 4;
    const int m0 = blockIdx.y * 128, n0 = blockIdx.x * 128;
    const int srow = t >> 3;          // 0..31
    const int scol = (t & 7) * 8;     // 0..56

    f32x4 acc[4][4] = {};

    const short* Ab = A + (size_t)(m0 + srow) * K + scol;
    const short* Bb = Bt + (size_t)(n0 + srow) * K + scol;

    for (int k0 = 0; k0 < K; k0 += 64) {
        __syncthreads();
#pragma unroll
        for (int i = 0; i < 4; i++) {
            gload_lds16(Ab + (size_t)(i * 32) * K + k0, As + i * 2048 + w * 512);
            gload_lds16(Bb + (size_t)(i * 32) * K + k0, Bs + i * 2048 + w * 512);
        }
        __syncthreads();
#pragma unroll
        for (int kk = 0; kk < 2; kk++) {
            bf16x8 af[4], bfr[4];
#pragma unroll
            for (int mi = 0; mi < 4; mi++)
                af[mi] = *(const bf16x8*)(As + (wr * 64 + mi * 16 + lr) * 64 + kk * 32 + lh * 8);
#pragma unroll
            for (int nj = 0; nj < 4; nj++)
                bfr[nj] = *(const bf16x8*)(Bs + (wc * 64 + nj * 16 + lr) * 64 + kk * 32 + lh * 8);
#pragma unroll
            for (int mi = 0; mi < 4; mi++)
#pragma unroll
                for (int nj = 0; nj < 4; nj++)
                    acc[mi][nj] = __builtin_amdgcn_mfma_f32_16x16x32_bf16(
                        af[mi], bfr[nj], acc[mi][nj], 0, 0, 0);
        }
    }
#pragma unroll
    for (int mi = 0; mi < 4; mi++) {
#pragma unroll
        for (int nj = 0; nj < 4; nj++) {
            const int row = m0 + wr * 64 + mi * 16 + lh * 4;
            const int col = n0 + wc * 64 + nj * 16 + lr;
            const float bsv = bias[col];
#pragma unroll
            for (int j = 0; j < 4; j++) {
                float v = acc[mi][nj][j] + bsv;
                if (OUTBF16)
                    ((short*)Cv)[(size_t)(row + j) * N + col] = f2bf(v);
                else
                    ((float*)Cv)[(size_t)(row + j) * N + col] = v;
            }
        }
    }
}

// ---------------- RoPE + scatter q,k -> [B,H,L,E]; q scaled by 1/8 ----------------
__global__ __launch_bounds__(256) void rope_scatter_k(const short* __restrict__ qkv,
                                                      const float* __restrict__ tab,
                                                      short* __restrict__ Q,
                                                      short* __restrict__ Kd) {
    int idx = blockIdx.x * 256 + threadIdx.x;   // B*L*H*32 = 4194304
    int d = idx & 31;
    int h = (idx >> 5) & 15;
    int bl = idx >> 9;          // b*L + l
    int l = bl & (L_SEQ - 1);
    int b = bl >> 11;
    float c = tab[l * 32 + d], s = tab[65536 + l * 32 + d];
    const short* row = qkv + (size_t)bl * 3072;
    float q1 = bf2f(row[h * 64 + d]);
    float q2 = bf2f(row[h * 64 + d + 32]);
    float k1 = bf2f(row[1024 + h * 64 + d]);
    float k2 = bf2f(row[1024 + h * 64 + d + 32]);
    size_t ob = ((size_t)((b * 16 + h) * 2048 + l)) * 64;
    const float sc = 0.125f;   // 1/sqrt(64) folded into q
    Q[ob + d]       = f2bf((q1 * c - q2 * s) * sc);
    Q[ob + d + 32]  = f2bf((q1 * s + q2 * c) * sc);
    Kd[ob + d]      = f2bf(k1 * c - k2 * s);
    Kd[ob + d + 32] = f2bf(k1 * s + k2 * c);
}

// ---------------- V transpose: qkv v-part -> Vt[B,H,E,L] ----------------
__global__ __launch_bounds__(256) void v_trans_k(const short* __restrict__ qkv,
                                                 short* __restrict__ Vt) {
    __shared__ short tile[64 * 65];
    int bh = blockIdx.y;
    int l0 = blockIdx.x * 64;
    int t = threadIdx.x;
    int b = bh >> 4, h = bh & 15;
#pragma unroll
    for (int i = 0; i < 16; i++) {
        int l = i * 4 + (t >> 6);
        int d = t & 63;
        tile[d * 65 + l] = qkv[(size_t)(b * 2048 + l0 + l) * 3072 + 2048 + h * 64 + d];
    }
    __syncthreads();
#pragma unroll
    for (int i = 0; i < 16; i++) {
        int d = i * 4 + (t >> 6);
        int l = t & 63;
        Vt[(size_t)(bh * 64 + d) * 2048 + l0 + l] = tile[d * 65 + l];
    }
}

// ---------------- flash attention: per (b,h), 128 q-rows/block ----------------
__global__ __launch_bounds__(256) void attn_k(const short* __restrict__ Q,
                                              const short* __restrict__ Kg,
                                              const short* __restrict__ Vt,
                                              short* __restrict__ O) {
    __shared__ short Ks[128 * 64];    // [k 128][d 64]
    __shared__ short Vs[64 * 128];    // [d 64][k 128]  (= Vt tile)
    __shared__ short Ps[4][32 * 128]; // per-wave P tile
    const int t = threadIdx.x;
    const int w = t >> 6, l = t & 63;
    const int lr = l & 15, lh = l >> 4;
    const int bh = blockIdx.y;
    const int q0 = blockIdx.x * 128;
    const short* Qb = Q + (size_t)bh * (2048 * 64);
    const short* Kb = Kg + (size_t)bh * (2048 * 64);
    const short* Vb = Vt + (size_t)bh * (64 * 2048);

    bf16x8 qf[2][2];
#pragma unroll
    for (int mi = 0; mi < 2; mi++)
#pragma unroll
        for (int kk = 0; kk < 2; kk++)
            qf[mi][kk] = *(const bf16x8*)(Qb + (size_t)(q0 + w * 32 + mi * 16 + lr) * 64 + kk * 32 + lh * 8);

    f32x4 o[2][4] = {};
    float mrow[2][4], lsum[2][4];
#pragma unroll
    for (int mi = 0; mi < 2; mi++)
#pragma unroll
        for (int j = 0; j < 4; j++) { mrow[mi][j] = -1e30f; lsum[mi][j] = 0.0f; }

    const int srow = t >> 3, scol = (t & 7) * 8;    // K staging
    const int vrow = t >> 4, vcol = (t & 15) * 8;   // V staging

    for (int k0 = 0; k0 < 2048; k0 += 128) {
        __syncthreads();
#pragma unroll
        for (int i = 0; i < 4; i++) {
            gload_lds16(Kb + (size_t)(k0 + i * 32 + srow) * 64 + scol, Ks + i * 2048 + w * 512);
            gload_lds16(Vb + (size_t)(i * 16 + vrow) * 2048 + k0 + vcol, Vs + i * 2048 + w * 512);
        }
        __syncthreads();

        // S = Q K^T  (q already scaled by 1/8)
        f32x4 s[2][8];
#pragma unroll
        for (int nj = 0; nj < 8; nj++) {
            bf16x8 kf0 = *(const bf16x8*)(Ks + (nj * 16 + lr) * 64 + lh * 8);
            bf16x8 kf1 = *(const bf16x8*)(Ks + (nj * 16 + lr) * 64 + 32 + lh * 8);
#pragma unroll
            for (int mi = 0; mi < 2; mi++) {
                f32x4 a = {};
                a = __builtin_amdgcn_mfma_f32_16x16x32_bf16(qf[mi][0], kf0, a, 0, 0, 0);
                a = __builtin_amdgcn_mfma_f32_16x16x32_bf16(qf[mi][1], kf1, a, 0, 0, 0);
                s[mi][nj] = a;
            }
        }

        // online softmax (rows live in 16-lane groups; reduce over lr via shfl_xor)
#pragma unroll
        for (int mi = 0; mi < 2; mi++) {
            float pm[4];
#pragma unroll
            for (int j = 0; j < 4; j++) {
                float v = s[mi][0][j];
#pragma unroll
                for (int nj = 1; nj < 8; nj++) v = fmaxf(v, s[mi][nj][j]);
                pm[j] = v;
            }
#pragma unroll
            for (int m = 1; m <= 8; m <<= 1)
#pragma unroll
                for (int j = 0; j < 4; j++) pm[j] = fmaxf(pm[j], __shfl_xor(pm[j], m));
            float scl[4];
#pragma unroll
            for (int j = 0; j < 4; j++) {
                float mn = fmaxf(mrow[mi][j], pm[j]);
                scl[j] = __expf(mrow[mi][j] - mn);
                mrow[mi][j] = mn;
            }
            float rs[4] = {0.f, 0.f, 0.f, 0.f};
#pragma unroll
            for (int nj = 0; nj < 8; nj++)
#pragma unroll
                for (int j = 0; j < 4; j++) {
                    float p = __expf(s[mi][nj][j] - mrow[mi][j]);
                    s[mi][nj][j] = p;
                    rs[j] += p;
                }
#pragma unroll
            for (int m = 1; m <= 8; m <<= 1)
#pragma unroll
                for (int j = 0; j < 4; j++) rs[j] += __shfl_xor(rs[j], m);
#pragma unroll
            for (int j = 0; j < 4; j++) lsum[mi][j] = lsum[mi][j] * scl[j] + rs[j];
#pragma unroll
            for (int nd = 0; nd < 4; nd++)
#pragma unroll
                for (int j = 0; j < 4; j++) o[mi][nd][j] *= scl[j];
            // P -> LDS (C-layout -> A-layout re-fragmentation)
#pragma unroll
            for (int nj = 0; nj < 8; nj++)
#pragma unroll
                for (int j = 0; j < 4; j++)
                    Ps[w][(mi * 16 + lh * 4 + j) * 128 + nj * 16 + lr] = f2bf(s[mi][nj][j]);
        }

        // O += P * V   (A = P from LDS, Bt = Vt tile)
#pragma unroll
        for (int kk = 0; kk < 4; kk++) {
            bf16x8 vf[4];
#pragma unroll
            for (int nd = 0; nd < 4; nd++)
                vf[nd] = *(const bf16x8*)(Vs + (nd * 16 + lr) * 128 + kk * 32 + lh * 8);
#pragma unroll
            for (int mi = 0; mi < 2; mi++) {
                bf16x8 pf = *(const bf16x8*)(&Ps[w][(mi * 16 + lr) * 128 + kk * 32 + lh * 8]);
#pragma unroll
                for (int nd = 0; nd < 4; nd++)
                    o[mi][nd] = __builtin_amdgcn_mfma_f32_16x16x32_bf16(pf, vf[nd], o[mi][nd], 0, 0, 0);
            }
        }
    }

    const int b = bh >> 4, h = bh & 15;
#pragma unroll
    for (int mi = 0; mi < 2; mi++) {
        float inv[4];
#pragma unroll
        for (int j = 0; j < 4; j++) inv[j] = 1.0f / lsum[mi][j];
#pragma unroll
        for (int nd = 0; nd < 4; nd++) {
            int col = h * 64 + nd * 16 + lr;
#pragma unroll
            for (int j = 0; j < 4; j++) {
                int grow = b * 2048 + q0 + w * 32 + mi * 16 + lh * 4 + j;
                O[(size_t)grow * 1024 + col] = f2bf(o[mi][nd][j] * inv[j]);
            }
        }
    }
}

extern "C" void kernel_launch(void* const* d_in, const int* in_sizes, int n_in,
                              void* d_out, int out_size, void* d_ws, size_t ws_size,
                              hipStream_t stream) {
    const float* x  = (const float*)d_in[0];
    const float* Wp = (const float*)d_in[1];
    const float* bp = (const float*)d_in[2];
    const float* Wo = (const float*)d_in[3];
    const float* bo = (const float*)d_in[4];

    char* ws = (char*)d_ws;
    const size_t SZ_XB  = (size_t)MTOT * DM * 2;       // 16 MB
    const size_t SZ_WPB = (size_t)3 * DM * DM * 2;     // 6 MB
    const size_t SZ_WOB = (size_t)DM * DM * 2;         // 2 MB
    const size_t SZ_QKV = (size_t)MTOT * 3 * DM * 2;   // 48 MB
    const size_t SZ_BHLE = (size_t)MTOT * DM * 2;      // 16 MB

    short* xb   = (short*)(ws);
    short* wpb  = (short*)(ws + SZ_XB);
    short* wob  = (short*)(ws + SZ_XB + SZ_WPB);
    short* qkvb = (short*)(ws + SZ_XB + SZ_WPB + SZ_WOB);
    short* Qb   = (short*)(ws + SZ_XB + SZ_WPB + SZ_WOB + SZ_QKV);
    short* Kb   = (short*)(ws + SZ_XB + SZ_WPB + SZ_WOB + SZ_QKV + SZ_BHLE);
    short* Vtb  = (short*)(ws + SZ_XB + SZ_WPB + SZ_WOB + SZ_QKV + 2 * SZ_BHLE);
    short* Ob   = (short*)(ws + SZ_XB + SZ_WPB + SZ_WOB + SZ_QKV + 3 * SZ_BHLE);
    float* tab  = (float*)(ws + SZ_XB + SZ_WPB + SZ_WOB + SZ_QKV + 4 * SZ_BHLE);

    cvt_k<<<8192, 256, 0, stream>>>(x, xb, MTOT * DM / 4);
    cvt_k<<<3072, 256, 0, stream>>>(Wp, wpb, 3 * DM * DM / 4);
    cvt_k<<<1024, 256, 0, stream>>>(Wo, wob, DM * DM / 4);
    rope_table_k<<<256, 256, 0, stream>>>(tab);

    gemm_bt_k<1><<<dim3(24, 64), 256, 0, stream>>>(xb, wpb, bp, qkvb, 3 * DM, DM);

    rope_scatter_k<<<16384, 256, 0, stream>>>(qkvb, tab, Qb, Kb);
    v_trans_k<<<dim3(32, 64), 256, 0, stream>>>(qkvb, Vtb);

    attn_k<<<dim3(16, 64), 256, 0, stream>>>(Qb, Kb, Vtb, Ob);

    gemm_bt_k<0><<<dim3(8, 64), 256, 0, stream>>>(Ob, wob, bo, d_out, DM, DM);
}

// Round 2
// 381.067 us; speedup vs baseline: 1.0023x; 1.0023x over previous
//
#include <hip/hip_runtime.h>
#include <hip/hip_bf16.h>
#include <stdint.h>

#define L_SEQ 2048
#define NB    4
#define NH    16
#define EH    64
#define DM    1024
#define MTOT  (NB * L_SEQ)   // 8192

typedef __attribute__((ext_vector_type(8))) short bf16x8;
typedef __attribute__((ext_vector_type(4))) float f32x4;

static __device__ __forceinline__ float bf2f(short u) {
    union { unsigned int i; float f; } c;
    c.i = ((unsigned int)(unsigned short)u) << 16;
    return c.f;
}
static __device__ __forceinline__ short f2bf(float f) {
    union { float f; unsigned int i; } c; c.f = f;
    unsigned int x = c.i;
    unsigned int r = (x + 0x7fffu + ((x >> 16) & 1u)) >> 16;
    return (short)(unsigned short)r;
}

// async global->LDS, 16B per lane; lds base must be wave-uniform (HW adds lane*16)
static __device__ __forceinline__ void gload_lds16(const void* g, void* lds) {
    __builtin_amdgcn_global_load_lds(
        (const __attribute__((address_space(1))) unsigned int*)g,
        (__attribute__((address_space(3))) unsigned int*)lds, 16, 0, 0);
}

// ---------------- elementwise fp32 -> bf16 ----------------
__global__ __launch_bounds__(256) void cvt_k(const float* __restrict__ in,
                                             short* __restrict__ out, int n4) {
    int i = blockIdx.x * 256 + threadIdx.x;
    if (i >= n4) return;
    float4 v = ((const float4*)in)[i];
    short4 o;
    o.x = f2bf(v.x); o.y = f2bf(v.y); o.z = f2bf(v.z); o.w = f2bf(v.w);
    ((short4*)out)[i] = o;
}

// ---------------- RoPE cos/sin table: [L][32] cos then [L][32] sin ----------------
__global__ __launch_bounds__(256) void rope_table_k(float* __restrict__ tab) {
    int i = blockIdx.x * 256 + threadIdx.x;   // 65536
    int l = i >> 5, d = i & 31;
    float inv = powf(10000.0f, -(float)d * (1.0f / 32.0f));
    float fr = (float)l * inv;
    tab[i]         = cosf(fr);
    tab[65536 + i] = sinf(fr);
}

// ---------------- GEMM C = A * Bt^T + bias ; A[M][K], Bt[N][K] row-major ----------------
template<int OUTBF16>
__global__ __launch_bounds__(256) void gemm_bt_k(const short* __restrict__ A,
                                                 const short* __restrict__ Bt,
                                                 const float* __restrict__ bias,
                                                 void* __restrict__ Cv,
                                                 int N, int K) {
    __shared__ short As[128 * 64];
    __shared__ short Bs[128 * 64];
    const int t = threadIdx.x;
    const int w = t >> 6, l = t & 63;
    const int wr = w >> 1, wc = w & 1;
    const int lr = l & 15, lh = l >> 4;
    const int m0 = blockIdx.y * 128, n0 = blockIdx.x * 128;
    const int srow = t >> 3;          // 0..31
    const int scol = (t & 7) * 8;     // 0..56

    f32x4 acc[4][4] = {};

    const short* Ab = A + (size_t)(m0 + srow) * K + scol;
    const short* Bb = Bt + (size_t)(n0 + srow) * K + scol;

    for (int k0 = 0; k0 < K; k0 += 64) {
        __syncthreads();
#pragma unroll
        for (int i = 0; i < 4; i++) {
            gload_lds16(Ab + (size_t)(i * 32) * K + k0, As + i * 2048 + w * 512);
            gload_lds16(Bb + (size_t)(i * 32) * K + k0, Bs + i * 2048 + w * 512);
        }
        __syncthreads();
#pragma unroll
        for (int kk = 0; kk < 2; kk++) {
            bf16x8 af[4], bfr[4];
#pragma unroll
            for (int mi = 0; mi < 4; mi++)
                af[mi] = *(const bf16x8*)(As + (wr * 64 + mi * 16 + lr) * 64 + kk * 32 + lh * 8);
#pragma unroll
            for (int nj = 0; nj < 4; nj++)
                bfr[nj] = *(const bf16x8*)(Bs + (wc * 64 + nj * 16 + lr) * 64 + kk * 32 + lh * 8);
            __builtin_amdgcn_s_setprio(1);
#pragma unroll
            for (int mi = 0; mi < 4; mi++)
#pragma unroll
                for (int nj = 0; nj < 4; nj++)
                    acc[mi][nj] = __builtin_amdgcn_mfma_f32_16x16x32_bf16(
                        af[mi], bfr[nj], acc[mi][nj], 0, 0, 0);
            __builtin_amdgcn_s_setprio(0);
        }
    }
#pragma unroll
    for (int mi = 0; mi < 4; mi++) {
#pragma unroll
        for (int nj = 0; nj < 4; nj++) {
            const int row = m0 + wr * 64 + mi * 16 + lh * 4;
            const int col = n0 + wc * 64 + nj * 16 + lr;
            const float bsv = bias[col];
#pragma unroll
            for (int j = 0; j < 4; j++) {
                float v = acc[mi][nj][j] + bsv;
                if (OUTBF16)
                    ((short*)Cv)[(size_t)(row + j) * N + col] = f2bf(v);
                else
                    ((float*)Cv)[(size_t)(row + j) * N + col] = v;
            }
        }
    }
}

// ---------------- RoPE + scatter q,k -> [B,H,L,E]; q scaled by 1/8 ----------------
// K rows are chunk-swizzled in global: 16B chunk c (of 8) stored at c ^ (l&7).
__global__ __launch_bounds__(256) void rope_scatter_k(const short* __restrict__ qkv,
                                                      const float* __restrict__ tab,
                                                      short* __restrict__ Q,
                                                      short* __restrict__ Kd) {
    int idx = blockIdx.x * 256 + threadIdx.x;   // B*L*H*32 = 4194304
    int d = idx & 31;
    int h = (idx >> 5) & 15;
    int bl = idx >> 9;          // b*L + l
    int l = bl & (L_SEQ - 1);
    int b = bl >> 11;
    float c = tab[l * 32 + d], s = tab[65536 + l * 32 + d];
    const short* row = qkv + (size_t)bl * 3072;
    float q1 = bf2f(row[h * 64 + d]);
    float q2 = bf2f(row[h * 64 + d + 32]);
    float k1 = bf2f(row[1024 + h * 64 + d]);
    float k2 = bf2f(row[1024 + h * 64 + d + 32]);
    size_t ob = ((size_t)((b * 16 + h) * 2048 + l)) * 64;
    const float sc = 0.125f;   // 1/sqrt(64) folded into q
    Q[ob + d]       = f2bf((q1 * c - q2 * s) * sc);
    Q[ob + d + 32]  = f2bf((q1 * s + q2 * c) * sc);
    int r7 = l & 7;
    int c1 = ((d >> 3) ^ r7) * 8 + (d & 7);
    int c2 = (((d >> 3) | 4) ^ r7) * 8 + (d & 7);
    Kd[ob + c1] = f2bf(k1 * c - k2 * s);
    Kd[ob + c2] = f2bf(k1 * s + k2 * c);
}

// ---------------- V transpose: qkv v-part -> Vt[B,H,E,L], swizzled ----------------
// Within each 128-l group (16 chunks of 8): low 3 bits of chunk idx XOR'd with d&7.
__global__ __launch_bounds__(256) void v_trans_k(const short* __restrict__ qkv,
                                                 short* __restrict__ Vt) {
    __shared__ short tile[64 * 65];
    int bh = blockIdx.y;
    int l0 = blockIdx.x * 64;
    int t = threadIdx.x;
    int b = bh >> 4, h = bh & 15;
#pragma unroll
    for (int i = 0; i < 16; i++) {
        int l = i * 4 + (t >> 6);
        int d = t & 63;
        tile[d * 65 + l] = qkv[(size_t)(b * 2048 + l0 + l) * 3072 + 2048 + h * 64 + d];
    }
    __syncthreads();
#pragma unroll
    for (int i = 0; i < 16; i++) {
        int d = i * 4 + (t >> 6);
        int lx = t & 63;
        int lg = l0 + lx;
        int ch = (lg >> 3) & 15;
        int chs = (ch & 8) | ((ch ^ d) & 7);
        Vt[(size_t)(bh * 64 + d) * 2048 + ((lg & ~127) | (chs << 3) | (lg & 7))]
            = tile[d * 65 + lx];
    }
}

// ---------------- flash attention: per (b,h), 128 q-rows/block, KVBLK=64 ----------------
__global__ __launch_bounds__(256, 4) void attn_k(const short* __restrict__ Q,
                                                 const short* __restrict__ Kg,
                                                 const short* __restrict__ Vt,
                                                 short* __restrict__ O) {
    __shared__ short Ks[64 * 64];     // [k 64][d 64], rows chunk-swizzled
    __shared__ short Vs[64 * 64];     // [d 64][k 64], rows chunk-swizzled
    __shared__ short Ps[4][32 * 64];  // per-wave P, rows chunk-swizzled
    const int t = threadIdx.x;
    const int w = t >> 6, l = t & 63;
    const int lr = l & 15, lh = l >> 4;
    const int r7 = lr & 7;

    // XCD-aware bijective swizzle of 1024 blocks (16 qblk x 64 bh)
    int fid = blockIdx.x + blockIdx.y * 16;
    int swz = (fid & 7) * 128 + (fid >> 3);
    const int qblk = swz & 15;
    const int bh = swz >> 4;
    const int q0 = qblk * 128;

    const short* Qb = Q + (size_t)bh * (2048 * 64);
    const short* Kb = Kg + (size_t)bh * (2048 * 64);
    const short* Vb = Vt + (size_t)bh * (64 * 2048);

    bf16x8 qf[2][2];
#pragma unroll
    for (int mi = 0; mi < 2; mi++)
#pragma unroll
        for (int kk = 0; kk < 2; kk++)
            qf[mi][kk] = *(const bf16x8*)(Qb + (size_t)(q0 + w * 32 + mi * 16 + lr) * 64 + kk * 32 + lh * 8);

    f32x4 o[2][4] = {};
    float mrow[2][4], lsum[2][4];
#pragma unroll
    for (int mi = 0; mi < 2; mi++)
#pragma unroll
        for (int j = 0; j < 4; j++) { mrow[mi][j] = -1e30f; lsum[mi][j] = 0.0f; }

    const int srow = t >> 3;          // 0..31
    const int scol = (t & 7) * 8;     // 0..56
    short* Pw = (short*)&Ps[w][0];

    for (int k0 = 0; k0 < 2048; k0 += 64) {
        __syncthreads();
        gload_lds16(Kb + (size_t)(k0 + srow) * 64 + scol,      Ks + w * 512);
        gload_lds16(Kb + (size_t)(k0 + 32 + srow) * 64 + scol, Ks + 2048 + w * 512);
        gload_lds16(Vb + (size_t)srow * 2048 + k0 + scol,        Vs + w * 512);
        gload_lds16(Vb + (size_t)(32 + srow) * 2048 + k0 + scol, Vs + 2048 + w * 512);
        __syncthreads();

        // S = Q K^T  (q already scaled by 1/8); s[mi][nj]: q-rows lh*4+j, k-col nj*16+lr
        f32x4 s[2][4];
#pragma unroll
        for (int nj = 0; nj < 4; nj++) {
            bf16x8 kf0 = *(const bf16x8*)(Ks + (nj * 16 + lr) * 64 + ((lh ^ r7) << 3));
            bf16x8 kf1 = *(const bf16x8*)(Ks + (nj * 16 + lr) * 64 + (((4 + lh) ^ r7) << 3));
            __builtin_amdgcn_s_setprio(1);
#pragma unroll
            for (int mi = 0; mi < 2; mi++) {
                f32x4 a = {};
                a = __builtin_amdgcn_mfma_f32_16x16x32_bf16(qf[mi][0], kf0, a, 0, 0, 0);
                a = __builtin_amdgcn_mfma_f32_16x16x32_bf16(qf[mi][1], kf1, a, 0, 0, 0);
                s[mi][nj] = a;
            }
            __builtin_amdgcn_s_setprio(0);
        }

        // online softmax + P write (LDS, swizzled)
#pragma unroll
        for (int mi = 0; mi < 2; mi++) {
            float pm[4];
#pragma unroll
            for (int j = 0; j < 4; j++) {
                float v = s[mi][0][j];
#pragma unroll
                for (int nj = 1; nj < 4; nj++) v = fmaxf(v, s[mi][nj][j]);
                pm[j] = v;
            }
#pragma unroll
            for (int m = 1; m <= 8; m <<= 1)
#pragma unroll
                for (int j = 0; j < 4; j++) pm[j] = fmaxf(pm[j], __shfl_xor(pm[j], m));
            float scl[4];
#pragma unroll
            for (int j = 0; j < 4; j++) {
                float mn = fmaxf(mrow[mi][j], pm[j]);
                scl[j] = __expf(mrow[mi][j] - mn);
                mrow[mi][j] = mn;
            }
            float rs[4] = {0.f, 0.f, 0.f, 0.f};
#pragma unroll
            for (int nj = 0; nj < 4; nj++)
#pragma unroll
                for (int j = 0; j < 4; j++) {
                    float p = __expf(s[mi][nj][j] - mrow[mi][j]);
                    s[mi][nj][j] = p;
                    rs[j] += p;
                }
#pragma unroll
            for (int m = 1; m <= 8; m <<= 1)
#pragma unroll
                for (int j = 0; j < 4; j++) rs[j] += __shfl_xor(rs[j], m);
#pragma unroll
            for (int j = 0; j < 4; j++) lsum[mi][j] = lsum[mi][j] * scl[j] + rs[j];
#pragma unroll
            for (int nd = 0; nd < 4; nd++)
#pragma unroll
                for (int j = 0; j < 4; j++) o[mi][nd][j] *= scl[j];
#pragma unroll
            for (int nj = 0; nj < 4; nj++)
#pragma unroll
                for (int j = 0; j < 4; j++) {
                    int prow = mi * 16 + lh * 4 + j;
                    int pc = ((2 * nj + (lr >> 3)) ^ (prow & 7)) * 8 + (lr & 7);
                    Pw[prow * 64 + pc] = f2bf(s[mi][nj][j]);
                }
        }

        // O += P * V
#pragma unroll
        for (int kk = 0; kk < 2; kk++) {
            bf16x8 pf0 = *(const bf16x8*)(Pw + (lr) * 64 + (((kk * 4 + lh) ^ r7) << 3));
            bf16x8 pf1 = *(const bf16x8*)(Pw + (16 + lr) * 64 + (((kk * 4 + lh) ^ r7) << 3));
#pragma unroll
            for (int nd = 0; nd < 4; nd++) {
                bf16x8 vf = *(const bf16x8*)(Vs + (nd * 16 + lr) * 64 + (((kk * 4 + lh) ^ r7) << 3));
                __builtin_amdgcn_s_setprio(1);
                o[0][nd] = __builtin_amdgcn_mfma_f32_16x16x32_bf16(pf0, vf, o[0][nd], 0, 0, 0);
                o[1][nd] = __builtin_amdgcn_mfma_f32_16x16x32_bf16(pf1, vf, o[1][nd], 0, 0, 0);
                __builtin_amdgcn_s_setprio(0);
            }
        }
    }

    const int b = bh >> 4, h = bh & 15;
#pragma unroll
    for (int mi = 0; mi < 2; mi++) {
        float inv[4];
#pragma unroll
        for (int j = 0; j < 4; j++) inv[j] = 1.0f / lsum[mi][j];
#pragma unroll
        for (int nd = 0; nd < 4; nd++) {
            int col = h * 64 + nd * 16 + lr;
#pragma unroll
            for (int j = 0; j < 4; j++) {
                int grow = b * 2048 + q0 + w * 32 + mi * 16 + lh * 4 + j;
                O[(size_t)grow * 1024 + col] = f2bf(o[mi][nd][j] * inv[j]);
            }
        }
    }
}

extern "C" void kernel_launch(void* const* d_in, const int* in_sizes, int n_in,
                              void* d_out, int out_size, void* d_ws, size_t ws_size,
                              hipStream_t stream) {
    const float* x  = (const float*)d_in[0];
    const float* Wp = (const float*)d_in[1];
    const float* bp = (const float*)d_in[2];
    const float* Wo = (const float*)d_in[3];
    const float* bo = (const float*)d_in[4];

    char* ws = (char*)d_ws;
    const size_t SZ_XB  = (size_t)MTOT * DM * 2;       // 16 MB
    const size_t SZ_WPB = (size_t)3 * DM * DM * 2;     // 6 MB
    const size_t SZ_WOB = (size_t)DM * DM * 2;         // 2 MB
    const size_t SZ_QKV = (size_t)MTOT * 3 * DM * 2;   // 48 MB
    const size_t SZ_BHLE = (size_t)MTOT * DM * 2;      // 16 MB

    short* xb   = (short*)(ws);
    short* wpb  = (short*)(ws + SZ_XB);
    short* wob  = (short*)(ws + SZ_XB + SZ_WPB);
    short* qkvb = (short*)(ws + SZ_XB + SZ_WPB + SZ_WOB);
    short* Qb   = (short*)(ws + SZ_XB + SZ_WPB + SZ_WOB + SZ_QKV);
    short* Kb   = (short*)(ws + SZ_XB + SZ_WPB + SZ_WOB + SZ_QKV + SZ_BHLE);
    short* Vtb  = (short*)(ws + SZ_XB + SZ_WPB + SZ_WOB + SZ_QKV + 2 * SZ_BHLE);
    short* Ob   = (short*)(ws + SZ_XB + SZ_WPB + SZ_WOB + SZ_QKV + 3 * SZ_BHLE);
    float* tab  = (float*)(ws + SZ_XB + SZ_WPB + SZ_WOB + SZ_QKV + 4 * SZ_BHLE);

    cvt_k<<<8192, 256, 0, stream>>>(x, xb, MTOT * DM / 4);
    cvt_k<<<3072, 256, 0, stream>>>(Wp, wpb, 3 * DM * DM / 4);
    cvt_k<<<1024, 256, 0, stream>>>(Wo, wob, DM * DM / 4);
    rope_table_k<<<256, 256, 0, stream>>>(tab);

    gemm_bt_k<1><<<dim3(24, 64), 256, 0, stream>>>(xb, wpb, bp, qkvb, 3 * DM, DM);

    rope_scatter_k<<<16384, 256, 0, stream>>>(qkvb, tab, Qb, Kb);
    v_trans_k<<<dim3(32, 64), 256, 0, stream>>>(qkvb, Vtb);

    attn_k<<<dim3(16, 64), 256, 0, stream>>>(Qb, Kb, Vtb, Ob);

    gemm_bt_k<0><<<dim3(8, 64), 256, 0, stream>>>(Ob, wob, bo, d_out, DM, DM);
}

// Round 4
// 220.279 us; speedup vs baseline: 1.7340x; 1.7299x over previous
//
#include <hip/hip_runtime.h>
#include <hip/hip_bf16.h>
#include <stdint.h>

#define L_SEQ 2048
#define NB    4
#define NH    16
#define EH    64
#define DM    1024
#define MTOT  (NB * L_SEQ)   // 8192

typedef __attribute__((ext_vector_type(8))) short bf16x8;
typedef __attribute__((ext_vector_type(4))) float f32x4;
typedef __attribute__((ext_vector_type(16))) float f32x16;
typedef __attribute__((ext_vector_type(2))) unsigned uint2v;

static __device__ __forceinline__ float bf2f(short u) {
    union { unsigned int i; float f; } c;
    c.i = ((unsigned int)(unsigned short)u) << 16;
    return c.f;
}
static __device__ __forceinline__ short f2bf(float f) {
    union { float f; unsigned int i; } c; c.f = f;
    unsigned int x = c.i;
    unsigned int r = (x + 0x7fffu + ((x >> 16) & 1u)) >> 16;
    return (short)(unsigned short)r;
}
static __device__ __forceinline__ unsigned cvtpk(float lo, float hi) {
    unsigned r;
    asm volatile("v_cvt_pk_bf16_f32 %0, %1, %2" : "=v"(r) : "v"(lo), "v"(hi));
    return r;
}
// combine across lane pair (l, l+32); correct under either permlane32_swap direction:
// r[0],r[1] are always {own, partner} in some order and OP is commutative.
static __device__ __forceinline__ float pairmax(float x) {
    union { float f; unsigned u; } c; c.f = x;
    uint2v r = __builtin_amdgcn_permlane32_swap(c.u, c.u, false, false);
    union { unsigned u; float f; } a, b; a.u = r[0]; b.u = r[1];
    return fmaxf(a.f, b.f);
}
static __device__ __forceinline__ float pairsum(float x) {
    union { float f; unsigned u; } c; c.f = x;
    uint2v r = __builtin_amdgcn_permlane32_swap(c.u, c.u, false, false);
    union { unsigned u; float f; } a, b; a.u = r[0]; b.u = r[1];
    return a.f + b.f;
}

// async global->LDS, 16B per lane; lds base must be wave-uniform (HW adds lane*16)
static __device__ __forceinline__ void gload_lds16(const void* g, void* lds) {
    __builtin_amdgcn_global_load_lds(
        (const __attribute__((address_space(1))) unsigned int*)g,
        (__attribute__((address_space(3))) unsigned int*)lds, 16, 0, 0);
}

// ---------------- elementwise fp32 -> bf16 ----------------
__global__ __launch_bounds__(256) void cvt_k(const float* __restrict__ in,
                                             short* __restrict__ out, int n4) {
    int i = blockIdx.x * 256 + threadIdx.x;
    if (i >= n4) return;
    float4 v = ((const float4*)in)[i];
    short4 o;
    o.x = f2bf(v.x); o.y = f2bf(v.y); o.z = f2bf(v.z); o.w = f2bf(v.w);
    ((short4*)out)[i] = o;
}

// ---------------- RoPE cos/sin table: [L][32] cos then [L][32] sin ----------------
__global__ __launch_bounds__(256) void rope_table_k(float* __restrict__ tab) {
    int i = blockIdx.x * 256 + threadIdx.x;   // 65536
    int l = i >> 5, d = i & 31;
    float inv = powf(10000.0f, -(float)d * (1.0f / 32.0f));
    float fr = (float)l * inv;
    tab[i]         = cosf(fr);
    tab[65536 + i] = sinf(fr);
}

// ---------------- GEMM C = A * Bt^T + bias ; A[M][K], Bt[N][K] row-major ----------------
template<int OUTBF16>
__global__ __launch_bounds__(256) void gemm_bt_k(const short* __restrict__ A,
                                                 const short* __restrict__ Bt,
                                                 const float* __restrict__ bias,
                                                 void* __restrict__ Cv,
                                                 int N, int K) {
    __shared__ short As[128 * 64];
    __shared__ short Bs[128 * 64];
    const int t = threadIdx.x;
    const int w = t >> 6, l = t & 63;
    const int wr = w >> 1, wc = w & 1;
    const int lr = l & 15, lh = l >> 4;
    const int m0 = blockIdx.y * 128, n0 = blockIdx.x * 128;
    const int srow = t >> 3;          // 0..31
    const int scol = (t & 7) * 8;     // 0..56

    f32x4 acc[4][4] = {};

    const short* Ab = A + (size_t)(m0 + srow) * K + scol;
    const short* Bb = Bt + (size_t)(n0 + srow) * K + scol;

    for (int k0 = 0; k0 < K; k0 += 64) {
        __syncthreads();
#pragma unroll
        for (int i = 0; i < 4; i++) {
            gload_lds16(Ab + (size_t)(i * 32) * K + k0, As + i * 2048 + w * 512);
            gload_lds16(Bb + (size_t)(i * 32) * K + k0, Bs + i * 2048 + w * 512);
        }
        __syncthreads();
#pragma unroll
        for (int kk = 0; kk < 2; kk++) {
            bf16x8 af[4], bfr[4];
#pragma unroll
            for (int mi = 0; mi < 4; mi++)
                af[mi] = *(const bf16x8*)(As + (wr * 64 + mi * 16 + lr) * 64 + kk * 32 + lh * 8);
#pragma unroll
            for (int nj = 0; nj < 4; nj++)
                bfr[nj] = *(const bf16x8*)(Bs + (wc * 64 + nj * 16 + lr) * 64 + kk * 32 + lh * 8);
            __builtin_amdgcn_s_setprio(1);
#pragma unroll
            for (int mi = 0; mi < 4; mi++)
#pragma unroll
                for (int nj = 0; nj < 4; nj++)
                    acc[mi][nj] = __builtin_amdgcn_mfma_f32_16x16x32_bf16(
                        af[mi], bfr[nj], acc[mi][nj], 0, 0, 0);
            __builtin_amdgcn_s_setprio(0);
        }
    }
#pragma unroll
    for (int mi = 0; mi < 4; mi++) {
#pragma unroll
        for (int nj = 0; nj < 4; nj++) {
            const int row = m0 + wr * 64 + mi * 16 + lh * 4;
            const int col = n0 + wc * 64 + nj * 16 + lr;
            const float bsv = bias[col];
#pragma unroll
            for (int j = 0; j < 4; j++) {
                float v = acc[mi][nj][j] + bsv;
                if (OUTBF16)
                    ((short*)Cv)[(size_t)(row + j) * N + col] = f2bf(v);
                else
                    ((float*)Cv)[(size_t)(row + j) * N + col] = v;
            }
        }
    }
}

// ---------------- RoPE + scatter q,k -> [B,H,L,E]; q scaled by log2e/8 ----------------
// K rows are chunk-swizzled in global: 16B chunk c (of 8) stored at c ^ (l&7).
__global__ __launch_bounds__(256) void rope_scatter_k(const short* __restrict__ qkv,
                                                      const float* __restrict__ tab,
                                                      short* __restrict__ Q,
                                                      short* __restrict__ Kd) {
    int idx = blockIdx.x * 256 + threadIdx.x;   // B*L*H*32 = 4194304
    int d = idx & 31;
    int h = (idx >> 5) & 15;
    int bl = idx >> 9;          // b*L + l
    int l = bl & (L_SEQ - 1);
    int b = bl >> 11;
    float c = tab[l * 32 + d], s = tab[65536 + l * 32 + d];
    const short* row = qkv + (size_t)bl * 3072;
    float q1 = bf2f(row[h * 64 + d]);
    float q2 = bf2f(row[h * 64 + d + 32]);
    float k1 = bf2f(row[1024 + h * 64 + d]);
    float k2 = bf2f(row[1024 + h * 64 + d + 32]);
    size_t ob = ((size_t)((b * 16 + h) * 2048 + l)) * 64;
    const float sc = 0.18033688011112042f;   // (1/8) * log2(e): scores in log2 domain
    Q[ob + d]       = f2bf((q1 * c - q2 * s) * sc);
    Q[ob + d + 32]  = f2bf((q1 * s + q2 * c) * sc);
    int r7 = l & 7;
    int c1 = ((d >> 3) ^ r7) * 8 + (d & 7);
    int c2 = (((d >> 3) | 4) ^ r7) * 8 + (d & 7);
    Kd[ob + c1] = f2bf(k1 * c - k2 * s);
    Kd[ob + c2] = f2bf(k1 * s + k2 * c);
}

// ---------------- V transpose: qkv v-part -> Vt[B,H,E,L] ----------------
// Column mapping within each 64-l tile: k -> sigma(k) (swap bit2<->bit3, matches the
// S^T C-layout -> PV B-layout register order), then chunk XOR (d&7) for bank-free reads.
__global__ __launch_bounds__(256) void v_trans_k(const short* __restrict__ qkv,
                                                 short* __restrict__ Vt) {
    __shared__ short tile[64 * 65];
    int bh = blockIdx.y;
    int l0 = blockIdx.x * 64;
    int t = threadIdx.x;
    int b = bh >> 4, h = bh & 15;
#pragma unroll
    for (int i = 0; i < 16; i++) {
        int l = i * 4 + (t >> 6);
        int d = t & 63;
        tile[d * 65 + l] = qkv[(size_t)(b * 2048 + l0 + l) * 3072 + 2048 + h * 64 + d];
    }
    __syncthreads();
#pragma unroll
    for (int i = 0; i < 16; i++) {
        int d = i * 4 + (t >> 6);
        int lx = t & 63;                         // k within 64-tile
        int cl = (lx & ~0xC) | ((lx & 4) << 1) | ((lx & 8) >> 1);   // sigma: bit2<->bit3
        int lp = l0 | ((((cl >> 3) ^ (d & 7)) << 3)) | (cl & 7);
        Vt[(size_t)(bh * 64 + d) * 2048 + lp] = tile[d * 65 + lx];
    }
}

// ---------------- flash attention, m214-style: 8 waves x 32 q-rows, KVBLK=64 ----------------
// Swapped QK^T (S^T = mfma(K,Q)): lane holds full 64-k P column for q = lane&31.
__global__ __launch_bounds__(512, 4) void attn_k(const short* __restrict__ Qg,
                                                 const short* __restrict__ Kg,
                                                 const short* __restrict__ Vt,
                                                 short* __restrict__ O) {
    __shared__ short Ks[2][64 * 64];
    __shared__ short Vs[2][64 * 64];
    const int t = threadIdx.x;
    const int w = t >> 6, l = t & 63;
    const int q = l & 31, hi = l >> 5;
    const int r7 = l & 7;

    // XCD-aware remap: co-locate the 8 q-blocks of each bh on one XCD
    const int od = blockIdx.x + blockIdx.y * 8;     // 0..511
    const int qblk = (od >> 3) & 7;
    const int bh = (od & 7) * 8 + (od >> 6);
    const int q0 = qblk * 256;

    const short* Qb = Qg + (size_t)bh * (2048 * 64);
    const short* Kb = Kg + (size_t)bh * (2048 * 64);
    const short* Vb = Vt + (size_t)bh * (64 * 2048);

    const int qrow = q0 + w * 32 + q;               // local row in [0,2048)
    bf16x8 qf[4];
#pragma unroll
    for (int ds = 0; ds < 4; ds++)
        qf[ds] = *(const bf16x8*)(Qb + (size_t)qrow * 64 + ds * 16 + hi * 8);

    f32x16 o0 = {}, o1 = {};
    float m = -1e30f, lsum = 0.0f;

    const int grow = w * 8 + (l >> 3);              // staging row 0..63
    const int gcol = r7 * 8;

    gload_lds16(Kb + (size_t)grow * 64 + gcol, &Ks[0][w * 512]);
    gload_lds16(Vb + (size_t)grow * 2048 + gcol, &Vs[0][w * 512]);
    __syncthreads();

    for (int it = 0; it < 32; ++it) {
        const int cur = it & 1;
        const short* Kc = &Ks[cur][0];
        const short* Vc = &Vs[cur][0];
        if (it < 31) {
            const int kn = (it + 1) * 64;
            gload_lds16(Kb + (size_t)(kn + grow) * 64 + gcol, &Ks[cur ^ 1][w * 512]);
            gload_lds16(Vb + (size_t)grow * 2048 + kn + gcol, &Vs[cur ^ 1][w * 512]);
        }

        // S^T = K * Q^T : C[k][q], col=lane&31=q, phys row=(reg&3)+8*(reg>>2)+4*hi
        f32x16 s0 = {}, s1 = {};
#pragma unroll
        for (int ds = 0; ds < 4; ds++) {
            const int ch = ((ds << 1) | hi) ^ r7;
            bf16x8 k0f = *(const bf16x8*)(Kc + q * 64 + ch * 8);
            bf16x8 k1f = *(const bf16x8*)(Kc + (32 + q) * 64 + ch * 8);
            __builtin_amdgcn_s_setprio(1);
            s0 = __builtin_amdgcn_mfma_f32_32x32x16_bf16(k0f, qf[ds], s0, 0, 0, 0);
            s1 = __builtin_amdgcn_mfma_f32_32x32x16_bf16(k1f, qf[ds], s1, 0, 0, 0);
            __builtin_amdgcn_s_setprio(0);
        }

        // in-lane max over 32 + lane-pair combine
        float tm[16];
#pragma unroll
        for (int r = 0; r < 16; r++) tm[r] = fmaxf(s0[r], s1[r]);
#pragma unroll
        for (int st = 8; st >= 1; st >>= 1)
#pragma unroll
            for (int i = 0; i < 8; i++) if (i < st) tm[i] = fmaxf(tm[i], tm[i + st]);
        float pm = pairmax(tm[0]);

        // defer-max: rescale only when max grew by > 8 (log2 units)
        if (__any((int)(pm > m + 8.0f))) {
            float mn = fmaxf(m, pm);
            float sc = __builtin_amdgcn_exp2f(m - mn);
            lsum *= sc;
#pragma unroll
            for (int r = 0; r < 16; r++) { o0[r] *= sc; o1[r] *= sc; }
            m = mn;
        }

        // P = exp2(S - m)
#pragma unroll
        for (int r = 0; r < 16; r++) {
            s0[r] = __builtin_amdgcn_exp2f(s0[r] - m);
            s1[r] = __builtin_amdgcn_exp2f(s1[r] - m);
        }
        float ts[16];
#pragma unroll
        for (int r = 0; r < 16; r++) ts[r] = s0[r] + s1[r];
#pragma unroll
        for (int st = 8; st >= 1; st >>= 1)
#pragma unroll
            for (int i = 0; i < 8; i++) if (i < st) ts[i] = ts[i] + ts[i + st];
        lsum += pairsum(ts[0]);

        // pack P in REGISTER ORDER (no cross-lane): B-slot k_B = ks*16 + hi*8 + j holds
        // phys k = (j&3)+8*(j>>2)+4*hi (+16*ks') -- the sigma permutation baked into Vt.
        bf16x8 pf[4];
        {
            union { unsigned u[4]; bf16x8 v; } f;
            f.u[0] = cvtpk(s0[0], s0[1]);  f.u[1] = cvtpk(s0[2], s0[3]);
            f.u[2] = cvtpk(s0[4], s0[5]);  f.u[3] = cvtpk(s0[6], s0[7]);
            pf[0] = f.v;
            f.u[0] = cvtpk(s0[8], s0[9]);  f.u[1] = cvtpk(s0[10], s0[11]);
            f.u[2] = cvtpk(s0[12], s0[13]); f.u[3] = cvtpk(s0[14], s0[15]);
            pf[1] = f.v;
            f.u[0] = cvtpk(s1[0], s1[1]);  f.u[1] = cvtpk(s1[2], s1[3]);
            f.u[2] = cvtpk(s1[4], s1[5]);  f.u[3] = cvtpk(s1[6], s1[7]);
            pf[2] = f.v;
            f.u[0] = cvtpk(s1[8], s1[9]);  f.u[1] = cvtpk(s1[10], s1[11]);
            f.u[2] = cvtpk(s1[12], s1[13]); f.u[3] = cvtpk(s1[14], s1[15]);
            pf[3] = f.v;
        }

        // O^T += V^T * P : C[d][q], col=lane&31=q, rows(regs)=d
#pragma unroll
        for (int ks = 0; ks < 4; ks++) {
            const int ch = ((ks << 1) | hi) ^ r7;
            bf16x8 v0f = *(const bf16x8*)(Vc + q * 64 + ch * 8);
            bf16x8 v1f = *(const bf16x8*)(Vc + (32 + q) * 64 + ch * 8);
            __builtin_amdgcn_s_setprio(1);
            o0 = __builtin_amdgcn_mfma_f32_32x32x16_bf16(v0f, pf[ks], o0, 0, 0, 0);
            o1 = __builtin_amdgcn_mfma_f32_32x32x16_bf16(v1f, pf[ks], o1, 0, 0, 0);
            __builtin_amdgcn_s_setprio(0);
        }

        __syncthreads();
    }

    const float inv = 1.0f / lsum;
    const int b = bh >> 4, h = bh & 15;
    short* Orow = O + (size_t)(b * 2048 + qrow) * 1024 + h * 64;
#pragma unroll
    for (int g = 0; g < 4; g++) {
        unsigned w0 = cvtpk(o0[g * 4 + 0] * inv, o0[g * 4 + 1] * inv);
        unsigned w1 = cvtpk(o0[g * 4 + 2] * inv, o0[g * 4 + 3] * inv);
        unsigned long long p0 = (unsigned long long)w0 | ((unsigned long long)w1 << 32);
        *(unsigned long long*)(Orow + g * 8 + hi * 4) = p0;
        unsigned w2 = cvtpk(o1[g * 4 + 0] * inv, o1[g * 4 + 1] * inv);
        unsigned w3 = cvtpk(o1[g * 4 + 2] * inv, o1[g * 4 + 3] * inv);
        unsigned long long p1 = (unsigned long long)w2 | ((unsigned long long)w3 << 32);
        *(unsigned long long*)(Orow + 32 + g * 8 + hi * 4) = p1;
    }
}

extern "C" void kernel_launch(void* const* d_in, const int* in_sizes, int n_in,
                              void* d_out, int out_size, void* d_ws, size_t ws_size,
                              hipStream_t stream) {
    const float* x  = (const float*)d_in[0];
    const float* Wp = (const float*)d_in[1];
    const float* bp = (const float*)d_in[2];
    const float* Wo = (const float*)d_in[3];
    const float* bo = (const float*)d_in[4];

    char* ws = (char*)d_ws;
    const size_t SZ_XB  = (size_t)MTOT * DM * 2;       // 16 MB
    const size_t SZ_WPB = (size_t)3 * DM * DM * 2;     // 6 MB
    const size_t SZ_WOB = (size_t)DM * DM * 2;         // 2 MB
    const size_t SZ_QKV = (size_t)MTOT * 3 * DM * 2;   // 48 MB
    const size_t SZ_BHLE = (size_t)MTOT * DM * 2;      // 16 MB

    short* xb   = (short*)(ws);
    short* wpb  = (short*)(ws + SZ_XB);
    short* wob  = (short*)(ws + SZ_XB + SZ_WPB);
    short* qkvb = (short*)(ws + SZ_XB + SZ_WPB + SZ_WOB);
    short* Qb   = (short*)(ws + SZ_XB + SZ_WPB + SZ_WOB + SZ_QKV);
    short* Kb   = (short*)(ws + SZ_XB + SZ_WPB + SZ_WOB + SZ_QKV + SZ_BHLE);
    short* Vtb  = (short*)(ws + SZ_XB + SZ_WPB + SZ_WOB + SZ_QKV + 2 * SZ_BHLE);
    short* Ob   = (short*)(ws + SZ_XB + SZ_WPB + SZ_WOB + SZ_QKV + 3 * SZ_BHLE);
    float* tab  = (float*)(ws + SZ_XB + SZ_WPB + SZ_WOB + SZ_QKV + 4 * SZ_BHLE);

    cvt_k<<<8192, 256, 0, stream>>>(x, xb, MTOT * DM / 4);
    cvt_k<<<3072, 256, 0, stream>>>(Wp, wpb, 3 * DM * DM / 4);
    cvt_k<<<1024, 256, 0, stream>>>(Wo, wob, DM * DM / 4);
    rope_table_k<<<256, 256, 0, stream>>>(tab);

    gemm_bt_k<1><<<dim3(24, 64), 256, 0, stream>>>(xb, wpb, bp, qkvb, 3 * DM, DM);

    rope_scatter_k<<<16384, 256, 0, stream>>>(qkvb, tab, Qb, Kb);
    v_trans_k<<<dim3(32, 64), 256, 0, stream>>>(qkvb, Vtb);

    attn_k<<<dim3(8, 64), 512, 0, stream>>>(Qb, Kb, Vtb, Ob);

    gemm_bt_k<0><<<dim3(8, 64), 256, 0, stream>>>(Ob, wob, bo, d_out, DM, DM);
}